// Round 8
// baseline (206.045 us; speedup 1.0000x reference)
//
#include <hip/hip_runtime.h>
#include <hip/hip_bf16.h>
#include <math.h>
#include <stdint.h>

// DiverseSiblingsSearch (lprobs (128,5,50257) f32, scores (128,5,10) f32, step=10)
//   lp = lprobs + scores[:,:,step-1,None]; per (b,beam) top-10 over vocab;
//   sibling penalty -0.5*(rank+1); per b top-10 of 50.
// Outputs concat as float32 values: scores[1280] | indices[1280] | beams[1280]
//
// Round-8: persistent blocks + register double-buffered tile pipeline.
//   r7 post-mortem: one-tile-per-block => every block drains all loads at a
//   barrier then runs a serial tail => load-issue duty cycle ~50%. Fix: each
//   block owns 5 tiles; tile k+1's 7 dwordx4 loads are issued BEFORE tile k's
//   tau/filter/extract, so memory stays busy through the tails (s_waitcnt
//   vmcnt(N>0), never full drain). LDS state (cand/sgrp/cnt) double-buffered
//   by tile parity; 2 barriers/tile. Hazard check: extraction of tile k
//   (reads cand[p]) vs filter of tile k+2 (writes cand[p]) is separated by
//   tile k+1's two barriers — safe.
//   tau/filter on RAW values (bias monotone, per-tile constant): tau = min of
//   16 group-maxes => >=16 survivors, E~54, chunk top-10 all >= tau. Bias
//   applied only to surviving keys (key = ford(x+bias)<<32 | ~idx — value
//   desc, index asc = jax top_k tie order; keys unique per chunk).

#define BS    256
#define KK    10
#define BEAM  5
#define NSLOT 7
#define CS    (BS * NSLOT * 4)   // 7168
#define CAP   512                // survivors expected ~54/tile
#define GRID  1024               // 4 blocks/CU co-resident
#define FCAP  2048

typedef unsigned long long u64;

// monotone float <-> uint map (no NaNs in log_softmax output)
__device__ __forceinline__ uint32_t ford(float x) {
    uint32_t u = __float_as_uint(x);
    return (u & 0x80000000u) ? ~u : (u | 0x80000000u);
}
__device__ __forceinline__ float funord(uint32_t u) {
    return __uint_as_float((u & 0x80000000u) ? (u & 0x7fffffffu) : ~u);
}

__device__ __forceinline__ void insert10(u64 (&key)[KK], u64 k) {
    if (k > key[KK - 1]) {
#pragma unroll
        for (int j = KK - 1; j >= 1; --j)
            key[j] = (k > key[j - 1]) ? key[j - 1] : ((k > key[j]) ? k : key[j]);
        if (k > key[0]) key[0] = k;
    }
}

struct Tile {
    float4 v[NSLOT];   // raw chunk elements (28/thread)
    float  xv;         // boundary leftover value (raw)
    int    xi;         // boundary leftover chunk-local index, -1 if none
    int    c0, len, pre;
    float  bias;
};

__device__ __forceinline__ void tile_load(
    Tile& T, int tile, int nc,
    const float* __restrict__ lprobs, const float* __restrict__ scores,
    int vocab, int sdim, int step, int tid)
{
    const int row   = tile / nc;
    const int chunk = tile - row * nc;
    T.bias = scores[(size_t)row * sdim + (step - 1)];
    T.c0 = chunk * CS;
    int len = vocab - T.c0; if (len > CS) len = CS;
    T.len = len;
    const float* cp = lprobs + (size_t)row * vocab + T.c0;
    int pre = (4 - (int)(((uintptr_t)cp >> 2) & 3)) & 3;
    if (pre > len) pre = len;
    T.pre = pre;
    const float4* g4 = (const float4*)(cp + pre);
    const int nvec = (len - pre) >> 2;
    const int done = pre + 4 * nvec;
    const int rem  = len - done;
#pragma unroll
    for (int i = 0; i < NSLOT; ++i) {
        int idx = tid + (i << 8);
        if (idx < nvec) T.v[i] = g4[idx];
        else { T.v[i].x = -INFINITY; T.v[i].y = -INFINITY;
               T.v[i].z = -INFINITY; T.v[i].w = -INFINITY; }
    }
    T.xv = -INFINITY; T.xi = -1;
    if (tid < pre)                      { T.xi = tid;            T.xv = cp[T.xi]; }
    else if (tid >= 4 && tid < 4 + rem) { T.xi = done + tid - 4; T.xv = cp[T.xi]; }
}

__device__ __forceinline__ void tile_process(
    const Tile& T, int p, int tile, int tid, int lane,
    u64 (*cand)[CAP], float (*sgrp)[16], int* s_cnt,
    u64* __restrict__ ws_keys)
{
    // per-thread raw max
    float m = T.xv;
#pragma unroll
    for (int i = 0; i < NSLOT; ++i)
        m = fmaxf(m, fmaxf(fmaxf(T.v[i].x, T.v[i].y), fmaxf(T.v[i].z, T.v[i].w)));

    // tau = min of 16 group-maxes (16-lane groups)
    float gm = m;
#pragma unroll
    for (int o = 1; o <= 8; o <<= 1) gm = fmaxf(gm, __shfl_xor(gm, o));
    if ((lane & 15) == 0) sgrp[p][(tid >> 6) * 4 + (lane >> 4)] = gm;
    if (tid == 0) s_cnt[p] = 0;
    __syncthreads();
    float tau = sgrp[p][0];
#pragma unroll
    for (int g = 1; g < 16; ++g) tau = fminf(tau, sgrp[p][g]);

    const float bias = T.bias;
    const int c0 = T.c0, len = T.len, pre = T.pre;
    auto app = [&](float x, int j) {            // j = chunk-local index
        if (j < len) {
            int pos = atomicAdd(&s_cnt[p], 1);
            if (pos < CAP)
                cand[p][pos] = ((u64)ford(x + bias) << 32) | (uint32_t)~(c0 + j);
        }
    };
#pragma unroll
    for (int i = 0; i < NSLOT; ++i) {
        int base = pre + ((tid + (i << 8)) << 2);
        if (T.v[i].x >= tau) app(T.v[i].x, base + 0);
        if (T.v[i].y >= tau) app(T.v[i].y, base + 1);
        if (T.v[i].z >= tau) app(T.v[i].z, base + 2);
        if (T.v[i].w >= tau) app(T.v[i].w, base + 3);
    }
    if (T.xi >= 0 && T.xv >= tau) app(T.xv, T.xi);
    __syncthreads();

    // extraction: rank-select (keys unique -> exact ranks), plain stores
    int n = s_cnt[p]; if (n > CAP) n = CAP;
    u64* outp = ws_keys + (size_t)tile * KK;
    if (tid < KK && tid >= n) outp[tid] = 0;    // pathological-shape guard
    for (int t2 = tid; t2 < n; t2 += BS) {
        u64 k = cand[p][t2];
        int rk = 0;
        for (int j = 0; j < n; ++j) rk += (cand[p][j] > k) ? 1 : 0;  // broadcast
        if (rk < KK) outp[rk] = k;
    }
}

__global__ __launch_bounds__(BS, 4) void dss_persist(
    const float* __restrict__ lprobs,
    const float* __restrict__ scores,
    const int*   __restrict__ step_ptr,
    int vocab, int sdim, int nc, int ntiles,
    u64* __restrict__ ws_keys)
{
    __shared__ u64   cand[2][CAP];
    __shared__ float sgrp[2][16];
    __shared__ int   s_cnt[2];

    const int tid  = threadIdx.x;
    const int lane = tid & 63;
    const int step = step_ptr[0];
    const int G    = gridDim.x;

    int t = blockIdx.x;
    if (t >= ntiles) return;

    Tile A, B;
    tile_load(A, t, nc, lprobs, scores, vocab, sdim, step, tid);
    for (;;) {
        const int tB = t + G;
        const bool hB = tB < ntiles;
        if (hB) tile_load(B, tB, nc, lprobs, scores, vocab, sdim, step, tid);
        tile_process(A, 0, t, tid, lane, cand, sgrp, s_cnt, ws_keys);
        if (!hB) break;

        const int tA = tB + G;
        const bool hA = tA < ntiles;
        if (hA) tile_load(A, tA, nc, lprobs, scores, vocab, sdim, step, tid);
        tile_process(B, 1, tB, tid, lane, cand, sgrp, s_cnt, ws_keys);
        if (!hA) break;
        t = tA;
    }
}

// per b: rank-select per beam (nc*10 -> 10, apply penalty), then 50 -> 10
__global__ __launch_bounds__(512) void dss_final(
    const u64* __restrict__ ws_keys,
    float* __restrict__ out, int bsz, int nc)
{
    const int b = blockIdx.x;
    const int t = threadIdx.x;
    const int NC  = nc * KK;            // <= 80
    const int tot = BEAM * NC;          // <= 400

    __shared__ u64  kbuf[BEAM * KK * 8];
    __shared__ float pen[BEAM * KK];
    __shared__ int   pidx[BEAM * KK];

    for (int i = t; i < tot; i += 512) kbuf[i] = ws_keys[(size_t)b * tot + i];
    __syncthreads();

    // phase 1: per-beam top-10 via rank-select (keys unique within a beam)
    if (t < tot) {
        int beam = t / NC;
        u64 k = kbuf[t];
        const u64* kb = kbuf + beam * NC;
        int r = 0;
        for (int j = 0; j < NC; ++j) r += (kb[j] > k) ? 1 : 0;
        if (r < KK) {
            pen [beam * KK + r] = funord((uint32_t)(k >> 32)) - 0.5f * (float)(r + 1);
            pidx[beam * KK + r] = (int)~(uint32_t)k;
        }
    }
    __syncthreads();

    // phase 2: top-10 of 50, ties -> lowest flat position (jax top_k order)
    if (t < BEAM * KK) {
        float p = pen[t];
        int r = 0;
        for (int j = 0; j < BEAM * KK; ++j) {
            float q = pen[j];
            r += (q > p || (q == p && j < t)) ? 1 : 0;
        }
        if (r < KK) {
            out[              b * KK + r] = p;
            out[(size_t)bsz * KK     + b * KK + r] = (float)pidx[t];
            out[(size_t)2 * bsz * KK + b * KK + r] = (float)(t / KK);
        }
    }
}

// ---------------- fallback (whole-row, two global passes) for tiny ws
__global__ __launch_bounds__(BS) void dss_row_topk(
    const float* __restrict__ lprobs,
    const float* __restrict__ scores,
    const int*   __restrict__ step_ptr,
    int vocab, int sdim,
    u64* __restrict__ ws_keys)
{
    const int row = blockIdx.x;
    const int tid = threadIdx.x;
    const int step = step_ptr[0];
    const float bias = scores[(size_t)row * sdim + (step - 1)];
    const float* rp = lprobs + (size_t)row * vocab;

    __shared__ u64  cand[FCAP];
    __shared__ u64  skey[BS * KK];
    __shared__ int  cnt;
    __shared__ float sh_tau;

    int pre = (4 - (int)(((uintptr_t)rp >> 2) & 3)) & 3;
    if (pre > vocab) pre = vocab;
    const float4* p4 = (const float4*)(rp + pre);
    const int nvec = (vocab - pre) >> 2;
    const int done = pre + 4 * nvec;
    const int rem  = vocab - done;

    float m = -INFINITY;
    if (tid < pre) m = rp[tid] + bias;
    for (int t = tid; t < nvec; t += BS) {
        float4 x = p4[t];
        m = fmaxf(m, fmaxf(fmaxf(x.x + bias, x.y + bias), fmaxf(x.z + bias, x.w + bias)));
    }
    if (tid < rem) m = fmaxf(m, rp[done + tid] + bias);

    skey[tid * KK] = ((u64)ford(m) << 32) | (uint32_t)~tid;
#pragma unroll
    for (int j = 1; j < KK; ++j) skey[tid * KK + j] = 0;
    if (tid == 0) cnt = 0;
    __syncthreads();
    for (int off = BS / 2; off >= 1; off >>= 1) {
        if (tid < off) {
            const int pa = tid * KK, pb = (tid + off) * KK;
            u64 mk[KK]; int ia = 0, ib = 0;
#pragma unroll
            for (int j = 0; j < KK; ++j) {
                u64 ka = skey[pa + ia], kb = skey[pb + ib];
                bool tA = (ka >= kb); mk[j] = tA ? ka : kb;
                if (tA) ++ia; else ++ib;
            }
#pragma unroll
            for (int j = 0; j < KK; ++j) skey[pa + j] = mk[j];
        }
        __syncthreads();
    }
    if (tid == 0) sh_tau = funord((uint32_t)(skey[9] >> 32));
    __syncthreads();
    const float tau = sh_tau;

    auto app = [&](float x, int i) {
        if (x >= tau) {
            int p = atomicAdd(&cnt, 1);
            if (p < FCAP) cand[p] = ((u64)ford(x) << 32) | (uint32_t)~i;
        }
    };
    if (tid < pre) app(rp[tid] + bias, tid);
    for (int t = tid; t < nvec; t += BS) {
        float4 x = p4[t];
        int base = pre + 4 * t;
        app(x.x + bias, base + 0); app(x.y + bias, base + 1);
        app(x.z + bias, base + 2); app(x.w + bias, base + 3);
    }
    if (tid < rem) app(rp[done + tid] + bias, done + tid);
    __syncthreads();

    const int n = (cnt < FCAP) ? cnt : FCAP;
    {
        u64 key[KK];
#pragma unroll
        for (int j = 0; j < KK; ++j) key[j] = 0;
        for (int i = tid; i < n; i += BS) insert10(key, cand[i]);
#pragma unroll
        for (int j = 0; j < KK; ++j) skey[tid * KK + j] = key[j];
    }
    __syncthreads();
    for (int off = BS / 2; off >= 1; off >>= 1) {
        if (tid < off) {
            const int pa = tid * KK, pb = (tid + off) * KK;
            u64 mk[KK]; int ia = 0, ib = 0;
#pragma unroll
            for (int j = 0; j < KK; ++j) {
                u64 ka = skey[pa + ia], kb = skey[pb + ib];
                bool tA = (ka >= kb); mk[j] = tA ? ka : kb;
                if (tA) ++ia; else ++ib;
            }
#pragma unroll
            for (int j = 0; j < KK; ++j) skey[pa + j] = mk[j];
        }
        __syncthreads();
    }
    if (tid < KK) ws_keys[(size_t)row * KK + tid] = skey[tid];
}

extern "C" void kernel_launch(void* const* d_in, const int* in_sizes, int n_in,
                              void* d_out, int out_size, void* d_ws, size_t ws_size,
                              hipStream_t stream)
{
    const float* lprobs = (const float*)d_in[0];
    const float* scores = (const float*)d_in[1];
    const int*   step   = (const int*)d_in[2];

    const int bsz   = 128;
    const int rows  = bsz * BEAM;                 // 640
    const int vocab = in_sizes[0] / rows;         // 50257
    const int sdim  = in_sizes[1] / rows;         // 10

    u64* ws_keys = (u64*)d_ws;

    int nc = (vocab + CS - 1) / CS;               // 8
    if (nc > 8) nc = 8;                           // kbuf sizing bound
    if (ws_size < (size_t)rows * nc * KK * sizeof(u64)) nc = 1;

    if (nc > 1) {
        const int ntiles = rows * nc;             // 5120
        int grid = GRID; if (grid > ntiles) grid = ntiles;
        dss_persist<<<grid, BS, 0, stream>>>(
            lprobs, scores, step, vocab, sdim, nc, ntiles, ws_keys);
    } else {
        dss_row_topk<<<rows, BS, 0, stream>>>(lprobs, scores, step, vocab, sdim, ws_keys);
    }
    dss_final<<<bsz, 512, 0, stream>>>(ws_keys, (float*)d_out, bsz, nc);
}